// Round 2
// baseline (248.986 us; speedup 1.0000x reference)
//
#include <hip/hip_runtime.h>
#include <hip/hip_bf16.h>

#define M_DIM 12608   // 64*197
#define K_DIM 768
#define N_DIM 3072
#define M_PAD 12800   // 100*128
#define BM 128
#define BN 128
#define BK 32
#define NT (K_DIM / BK)     // 24 K-tiles
#define MBLK (M_PAD / BM)   // 100
#define NBLK (N_DIM / BN)   // 24
#define NWG (MBLK * NBLK)   // 2400, divisible by 8

typedef __attribute__((ext_vector_type(8))) short bf16x8;
typedef __attribute__((ext_vector_type(4))) float f32x4;

__device__ __forceinline__ void gload_lds16(const void* g, void* l) {
  __builtin_amdgcn_global_load_lds(
      (const __attribute__((address_space(1))) unsigned int*)g,
      (__attribute__((address_space(3))) unsigned int*)l,
      16, 0, 0);
}

// Fused convert: blocks [0, GX) do x fp32->bf16 (+M_PAD zero tail),
// blocks [GX, GX+GW) do 2:4 mask + w fp32->bf16.
#define GX 4800   // M_PAD*K/8/256
#define GW 2304   // N*(K/4)/256
__global__ void cvt_fused(const float* __restrict__ x, const float* __restrict__ w,
                          __hip_bfloat16* __restrict__ xb, __hip_bfloat16* __restrict__ wb) {
  if (blockIdx.x < GX) {
    size_t i = ((size_t)blockIdx.x * 256 + threadIdx.x) * 8;
    union { __hip_bfloat16 h[8]; uint4 u; } o;
    if (i < (size_t)M_DIM * K_DIM) {
      float4 a = *(const float4*)(x + i);
      float4 b = *(const float4*)(x + i + 4);
      o.h[0] = __float2bfloat16(a.x); o.h[1] = __float2bfloat16(a.y);
      o.h[2] = __float2bfloat16(a.z); o.h[3] = __float2bfloat16(a.w);
      o.h[4] = __float2bfloat16(b.x); o.h[5] = __float2bfloat16(b.y);
      o.h[6] = __float2bfloat16(b.z); o.h[7] = __float2bfloat16(b.w);
    } else {
      o.u = make_uint4(0, 0, 0, 0);
    }
    *(uint4*)(xb + i) = o.u;
  } else {
    size_t g = ((size_t)(blockIdx.x - GX) * 256 + threadIdx.x);
    float4 v = *(const float4*)(w + g * 4);
    float val[4] = {v.x, v.y, v.z, v.w};
    float a[4] = {fabsf(v.x), fabsf(v.y), fabsf(v.z), fabsf(v.w)};
    union { __hip_bfloat16 h[4]; uint2 u; } o;
#pragma unroll
    for (int i = 0; i < 4; ++i) {
      int rank = 0;
#pragma unroll
      for (int j = 0; j < 4; ++j)
        rank += (a[j] > a[i]) || (a[j] == a[i] && j > i);
      o.h[i] = __float2bfloat16(rank < 2 ? val[i] : 0.0f);
    }
    *(uint2*)(wb + g * 4) = o.u;
  }
}

// 128x128 tile, BK=32, 4 waves (2Mx2N), per-wave 64x64 output (4x4 MFMA frags).
// m97-style 2-buffer loop (one __syncthreads per K-tile; drain covered by
// multi-block residency: 32KB LDS + <=128 VGPR -> 4 blocks/CU), XOR-swizzled
// LDS via pre-swizzled global source, direct-store epilogue (no LDS, no
// barriers -> store drain of one block overlaps compute of the other 3).
//
// LDS buffer q at q*16384: A 128x32 bf16 (8KB) @ +0, B 128x32 @ +8192.
// Element (row, kg) at byte row*64 + (kg ^ (row&3) ^ ((row>>2)&3))*16.
__global__ __launch_bounds__(256, 4) void gemm_bt(
    const __hip_bfloat16* __restrict__ A,   // [M_PAD][K]
    const __hip_bfloat16* __restrict__ B,   // [N][K]
    const float* __restrict__ bias,         // [N]
    float* __restrict__ C)                  // [M][N]
{
  __shared__ char smem[32768];

  const int tid  = threadIdx.x;
  const int lane = tid & 63;
  const int wave = tid >> 6;   // 0..3
  const int wm   = wave >> 1;  // 0..1 (M half)
  const int wn   = wave & 1;   // 0..1 (N half)

  // bijective XCD swizzle: 2400 = 8 * 300; consecutive swz iterate N fastest
  const int wg  = blockIdx.x;
  const int swz = (wg & 7) * (NWG / 8) + (wg >> 3);
  const int tile_m = (swz / NBLK) * BM;
  const int tile_n = (swz % NBLK) * BN;

  // ---- staging geometry: one gload issue = 4 waves x 16 rows x 64B (4KB)
  // lane l -> row r2 = l>>2, physical slot p = l&3; global k-group = p ^ f(row)
  // (f(row)=f(r2) because all row bases are multiples of 16)
  const int r2 = lane >> 2;
  const int p  = lane & 3;
  const int gsw = p ^ (r2 & 3) ^ ((r2 >> 2) & 3);
  const __hip_bfloat16* asrc[2];
  const __hip_bfloat16* bsrc[2];
#pragma unroll
  for (int u = 0; u < 2; ++u) {
    const int row = wave * 32 + u * 16 + r2;
    asrc[u] = A + (size_t)(tile_m + row) * K_DIM + gsw * 8;
    bsrc[u] = B + (size_t)(tile_n + row) * K_DIM + gsw * 8;
  }

  // ---- fragment read geometry (A/B operand: row = lane&15, k-group = lane>>4)
  const int frow  = lane & 15;
  const int fslot = (lane >> 4) ^ (frow & 3) ^ ((frow >> 2) & 3);
  const int abase = (wm * 64 + frow) * 64 + fslot * 16;           // + q*16384 + m*1024
  const int bbase = 8192 + (wn * 64 + frow) * 64 + fslot * 16;    // + q*16384 + n*1024

  f32x4 acc[4][4] = {};

  // ---- prologue: stage tile 0 into buffer 0
#pragma unroll
  for (int u = 0; u < 2; ++u)
    gload_lds16(asrc[u], smem + (wave * 2 + u) * 1024);
#pragma unroll
  for (int u = 0; u < 2; ++u)
    gload_lds16(bsrc[u], smem + 8192 + (wave * 2 + u) * 1024);

  // ---- main loop: one barrier per K-tile (m97 pattern)
  for (int t = 0; t < NT; ++t) {
    __syncthreads();   // drains vmcnt (tile t resident) + lgkmcnt (buf reuse safe)

    if (t + 1 < NT) {
      char* nb = smem + ((t + 1) & 1) * 16384;
      const int off = (t + 1) * BK;
#pragma unroll
      for (int u = 0; u < 2; ++u)
        gload_lds16(asrc[u] + off, nb + (wave * 2 + u) * 1024);
#pragma unroll
      for (int u = 0; u < 2; ++u)
        gload_lds16(bsrc[u] + off, nb + 8192 + (wave * 2 + u) * 1024);
    }

    const char* bq = smem + (t & 1) * 16384;
    bf16x8 af[4], bfv[4];
#pragma unroll
    for (int m = 0; m < 4; ++m)
      af[m] = *(const bf16x8*)(bq + abase + m * 1024);
#pragma unroll
    for (int n = 0; n < 4; ++n)
      bfv[n] = *(const bf16x8*)(bq + bbase + n * 1024);
#pragma unroll
    for (int m = 0; m < 4; ++m)
#pragma unroll
      for (int n = 0; n < 4; ++n)
        acc[m][n] = __builtin_amdgcn_mfma_f32_16x16x32_bf16(af[m], bfv[n], acc[m][n], 0, 0, 0);
  }

  // ---- epilogue: direct stores (no LDS round-trip, no barriers).
  // C/D frag layout: col = lane&15, row = (lane>>4)*4 + reg.
  // Each store inst: 4 rows x 64B contiguous segments; adjacent n-insts fill
  // adjacent 64B of the same rows -> L2 write-combines to full lines.
  const int ccol = lane & 15;
  const int quad = lane >> 4;
  float bv[4];
#pragma unroll
  for (int n = 0; n < 4; ++n)
    bv[n] = bias[tile_n + wn * 64 + n * 16 + ccol];

#pragma unroll
  for (int m = 0; m < 4; ++m) {
    const int rbase = tile_m + wm * 64 + m * 16 + quad * 4;
#pragma unroll
    for (int r = 0; r < 4; ++r) {
      const int grow = rbase + r;
      if (grow < M_DIM) {
        float* crow = C + (size_t)grow * N_DIM + tile_n + wn * 64;
#pragma unroll
        for (int n = 0; n < 4; ++n)
          crow[n * 16 + ccol] = acc[m][n][r] + bv[n];
      }
    }
  }
}

extern "C" void kernel_launch(void* const* d_in, const int* in_sizes, int n_in,
                              void* d_out, int out_size, void* d_ws, size_t ws_size,
                              hipStream_t stream) {
  const float* x    = (const float*)d_in[0];
  const float* w    = (const float*)d_in[1];
  const float* bias = (const float*)d_in[2];
  float* out = (float*)d_out;

  __hip_bfloat16* xb = (__hip_bfloat16*)d_ws;                  // [M_PAD][K]
  __hip_bfloat16* wb = xb + (size_t)M_PAD * K_DIM;             // [N][K]

  cvt_fused<<<GX + GW, 256, 0, stream>>>(x, w, xb, wb);
  gemm_bt<<<NWG, 256, 0, stream>>>(xb, wb, bias, out);
}

// Round 3
// 248.168 us; speedup vs baseline: 1.0033x; 1.0033x over previous
//
#include <hip/hip_runtime.h>
#include <hip/hip_bf16.h>

#define M_DIM 12608   // 64*197
#define K_DIM 768
#define N_DIM 3072
#define M_PAD 12800   // 100*128
#define BM 128
#define BN 128
#define BK 32
#define NT (K_DIM / BK)     // 24 K-tiles
#define MBLK (M_PAD / BM)   // 100
#define NBLK (N_DIM / BN)   // 24
#define NWG (MBLK * NBLK)   // 2400, divisible by 8

typedef __attribute__((ext_vector_type(8))) short bf16x8;
typedef __attribute__((ext_vector_type(4))) float f32x4;

__device__ __forceinline__ void gload_lds16(const void* g, void* l) {
  __builtin_amdgcn_global_load_lds(
      (const __attribute__((address_space(1))) unsigned int*)g,
      (__attribute__((address_space(3))) unsigned int*)l,
      16, 0, 0);
}

// Fused convert: blocks [0, GX) do x fp32->bf16 (+M_PAD zero tail),
// blocks [GX, GX+GW) do 2:4 mask + w fp32->bf16.
#define GX 4800   // M_PAD*K/8/256
#define GW 2304   // N*(K/4)/256
__global__ void cvt_fused(const float* __restrict__ x, const float* __restrict__ w,
                          __hip_bfloat16* __restrict__ xb, __hip_bfloat16* __restrict__ wb) {
  if (blockIdx.x < GX) {
    size_t i = ((size_t)blockIdx.x * 256 + threadIdx.x) * 8;
    union { __hip_bfloat16 h[8]; uint4 u; } o;
    if (i < (size_t)M_DIM * K_DIM) {
      float4 a = *(const float4*)(x + i);
      float4 b = *(const float4*)(x + i + 4);
      o.h[0] = __float2bfloat16(a.x); o.h[1] = __float2bfloat16(a.y);
      o.h[2] = __float2bfloat16(a.z); o.h[3] = __float2bfloat16(a.w);
      o.h[4] = __float2bfloat16(b.x); o.h[5] = __float2bfloat16(b.y);
      o.h[6] = __float2bfloat16(b.z); o.h[7] = __float2bfloat16(b.w);
    } else {
      o.u = make_uint4(0, 0, 0, 0);
    }
    *(uint4*)(xb + i) = o.u;
  } else {
    size_t g = ((size_t)(blockIdx.x - GX) * 256 + threadIdx.x);
    float4 v = *(const float4*)(w + g * 4);
    float val[4] = {v.x, v.y, v.z, v.w};
    float a[4] = {fabsf(v.x), fabsf(v.y), fabsf(v.z), fabsf(v.w)};
    union { __hip_bfloat16 h[4]; uint2 u; } o;
#pragma unroll
    for (int i = 0; i < 4; ++i) {
      int rank = 0;
#pragma unroll
      for (int j = 0; j < 4; ++j)
        rank += (a[j] > a[i]) || (a[j] == a[i] && j > i);
      o.h[i] = __float2bfloat16(rank < 2 ? val[i] : 0.0f);
    }
    *(uint2*)(wb + g * 4) = o.u;
  }
}

// 128x128 tile, BK=32, 4 waves (2Mx2N), per-wave 64x64 output (4x4 MFMA frags).
// 3-deep LDS K-tile pipeline (3 x 16KB = 48KB -> 3 blocks/CU), counted
// vmcnt(4) + ONE raw s_barrier per K-tile (no vmcnt(0) drain in steady state),
// setprio around the MFMA cluster, direct-store epilogue (no LDS, no barriers
// -> store drain of one block overlaps compute of the other two).
//
// LDS buffer q at q*16384: A 128x32 bf16 (8KB) @ +0, B 128x32 @ +8192.
// Swizzle: element (row, kg) at byte row*64 + (kg ^ ((row>>1)&3))*16.
// Proof of 2-way max on frag reads: within a 16-lane group the byte addr
// mod 128 is (row&1)*64 + (kg^f(row))*16; (row&1, f(row)) covers all 8
// combos exactly twice over rows 0..15 -> every 16B bank slot hit exactly
// twice (2-way aliasing is free, m136).
// gload_lds writes linearly (wave base + lane*16); swizzle is applied by
// pre-swizzling the per-lane GLOBAL source k-group (both-sides rule #21).
__global__ __launch_bounds__(256, 3) void gemm_bt(
    const __hip_bfloat16* __restrict__ A,   // [M_PAD][K]
    const __hip_bfloat16* __restrict__ B,   // [N][K]
    const float* __restrict__ bias,         // [N]
    float* __restrict__ C)                  // [M][N]
{
  __shared__ char smem[49152];

  const int tid  = threadIdx.x;
  const int lane = tid & 63;
  const int wave = tid >> 6;   // 0..3
  const int wm   = wave >> 1;  // 0..1 (M half)
  const int wn   = wave & 1;   // 0..1 (N half)

  // bijective XCD swizzle: 2400 = 8 * 300; consecutive swz iterate N fastest
  const int wg  = blockIdx.x;
  const int swz = (wg & 7) * (NWG / 8) + (wg >> 3);
  const int tile_m = (swz / NBLK) * BM;
  const int tile_n = (swz % NBLK) * BN;

  // ---- staging geometry: one gload issue = 4 waves x 16 rows x 64B (4KB)
  // lane l -> row r2 = l>>2, physical slot p = l&3; global k-group = p ^ f(row)
  // f(row) = (row>>1)&3 = (r2>>1)&3 (row bases are multiples of 16)
  const int r2 = lane >> 2;
  const int p  = lane & 3;
  const int gsw = p ^ ((r2 >> 1) & 3);
  const __hip_bfloat16* asrc[2];
  const __hip_bfloat16* bsrc[2];
#pragma unroll
  for (int u = 0; u < 2; ++u) {
    const int row = wave * 32 + u * 16 + r2;
    asrc[u] = A + (size_t)(tile_m + row) * K_DIM + gsw * 8;
    bsrc[u] = B + (size_t)(tile_n + row) * K_DIM + gsw * 8;
  }

  // ---- fragment read geometry (A/B operand: row = lane&15, k-group = lane>>4)
  const int frow  = lane & 15;
  const int fslot = (lane >> 4) ^ ((frow >> 1) & 3);
  const int abase = (wm * 64 + frow) * 64 + fslot * 16;           // + q*16384 + m*1024
  const int bbase = 8192 + (wn * 64 + frow) * 64 + fslot * 16;    // + q*16384 + n*1024

  f32x4 acc[4][4] = {};

  // ---- prologue: stage tiles 0 and 1 into buffers 0 and 1 (8 issues)
#pragma unroll
  for (int u = 0; u < 2; ++u)
    gload_lds16(asrc[u], smem + (wave * 2 + u) * 1024);
#pragma unroll
  for (int u = 0; u < 2; ++u)
    gload_lds16(bsrc[u], smem + 8192 + (wave * 2 + u) * 1024);
#pragma unroll
  for (int u = 0; u < 2; ++u)
    gload_lds16(asrc[u] + BK, smem + 16384 + (wave * 2 + u) * 1024);
#pragma unroll
  for (int u = 0; u < 2; ++u)
    gload_lds16(bsrc[u] + BK, smem + 16384 + 8192 + (wave * 2 + u) * 1024);

  // ---- main loop: tile t in buf (t%3); stage t+2 into buf ((t+2)%3).
  // vmcnt(4): own outstanding <= {stage(t):4, stage(t+1):4}; waiting to 4
  // retires stage(t) (FIFO, m135). Barrier then makes ALL waves' tile-t
  // writes visible AND proves all waves consumed tile t-1 (their t-1
  // ds_reads were lgkmcnt-retired before their t-1 MFMAs, which precede
  // this barrier) -> safe to overwrite buf((t+2)%3) == buf((t-1)%3).
#pragma unroll 3
  for (int t = 0; t < NT; ++t) {
    if (t < NT - 1) { asm volatile("s_waitcnt vmcnt(4)" ::: "memory"); }
    else            { asm volatile("s_waitcnt vmcnt(0)" ::: "memory"); }
    __builtin_amdgcn_s_barrier();

    if (t + 2 < NT) {
      char* nb = smem + ((t + 2) % 3) * 16384;
      const int off = (t + 2) * BK;
#pragma unroll
      for (int u = 0; u < 2; ++u)
        gload_lds16(asrc[u] + off, nb + (wave * 2 + u) * 1024);
#pragma unroll
      for (int u = 0; u < 2; ++u)
        gload_lds16(bsrc[u] + off, nb + 8192 + (wave * 2 + u) * 1024);
    }

    const char* bq = smem + (t % 3) * 16384;
    bf16x8 af[4], bfv[4];
#pragma unroll
    for (int m = 0; m < 4; ++m)
      af[m] = *(const bf16x8*)(bq + abase + m * 1024);
#pragma unroll
    for (int n = 0; n < 4; ++n)
      bfv[n] = *(const bf16x8*)(bq + bbase + n * 1024);
    __builtin_amdgcn_s_setprio(1);
#pragma unroll
    for (int m = 0; m < 4; ++m)
#pragma unroll
      for (int n = 0; n < 4; ++n)
        acc[m][n] = __builtin_amdgcn_mfma_f32_16x16x32_bf16(af[m], bfv[n], acc[m][n], 0, 0, 0);
    __builtin_amdgcn_s_setprio(0);
  }

  // ---- epilogue: direct stores (no LDS round-trip, no barriers).
  // C/D frag layout: col = lane&15, row = (lane>>4)*4 + reg.
  // Each store inst: 4 rows x 64B contiguous segments; adjacent n-insts fill
  // adjacent 64B of the same rows -> L2 write-combines to full lines.
  const int ccol = lane & 15;
  const int quad = lane >> 4;
  float bv[4];
#pragma unroll
  for (int n = 0; n < 4; ++n)
    bv[n] = bias[tile_n + wn * 64 + n * 16 + ccol];

#pragma unroll
  for (int m = 0; m < 4; ++m) {
    const int rbase = tile_m + wm * 64 + m * 16 + quad * 4;
#pragma unroll
    for (int r = 0; r < 4; ++r) {
      const int grow = rbase + r;
      if (grow < M_DIM) {
        float* crow = C + (size_t)grow * N_DIM + tile_n + wn * 64;
#pragma unroll
        for (int n = 0; n < 4; ++n)
          crow[n * 16 + ccol] = acc[m][n][r] + bv[n];
      }
    }
  }
}

extern "C" void kernel_launch(void* const* d_in, const int* in_sizes, int n_in,
                              void* d_out, int out_size, void* d_ws, size_t ws_size,
                              hipStream_t stream) {
  const float* x    = (const float*)d_in[0];
  const float* w    = (const float*)d_in[1];
  const float* bias = (const float*)d_in[2];
  float* out = (float*)d_out;

  __hip_bfloat16* xb = (__hip_bfloat16*)d_ws;                  // [M_PAD][K]
  __hip_bfloat16* wb = xb + (size_t)M_PAD * K_DIM;             // [N][K]

  cvt_fused<<<GX + GW, 256, 0, stream>>>(x, w, xb, wb);
  gemm_bt<<<NWG, 256, 0, stream>>>(xb, wb, bias, out);
}